// Round 5
// baseline (54.641 us; speedup 1.0000x reference)
//
#include <hip/hip_runtime.h>

// LIF_BTN: y[t] = heaviside(tau*v[t-1] + x[t] - v_th), v[t] = (spike ? 0 : m)
// x: [T=32, B=32, N=32768] f32; y same. Memory-bound.
// R4: revert R3's asm store (broke compiler scheduling, -18%); back to
// __builtin_nontemporal_store. Deepen prefetch window 8 -> 16 (32 data VGPRs,
// total ~44 < 64-VGPR occupancy cliff) to double per-wave outstanding loads.
// FETCH_SIZE floor of ~65 MB is harness-imposed (537 MB memset between
// replays thrashes L3) - not addressable from the kernel.

typedef float f32x2 __attribute__((ext_vector_type(2)));

#define T_STEPS 32
#define CHUNK 16
#define TAU 0.5f
#define V_TH 1.0f

__global__ __launch_bounds__(256) void lif_btn_kernel(
    const f32x2* __restrict__ x, f32x2* __restrict__ y, int n2) {
    int idx = blockIdx.x * blockDim.x + threadIdx.x;
    if (idx >= n2) return;

    const f32x2* xp = x + idx;
    f32x2* yp = y + idx;

    f32x2 v;
    v.x = 0.f; v.y = 0.f;

    f32x2 cur[CHUNK], nxt[CHUNK];

    #pragma unroll
    for (int i = 0; i < CHUNK; ++i)
        cur[i] = xp[(size_t)i * n2];

    #pragma unroll
    for (int c = 0; c < T_STEPS / CHUNK; ++c) {
        if (c + 1 < T_STEPS / CHUNK) {
            #pragma unroll
            for (int i = 0; i < CHUNK; ++i)
                nxt[i] = xp[(size_t)((c + 1) * CHUNK + i) * n2];
        }
        #pragma unroll
        for (int i = 0; i < CHUNK; ++i) {
            f32x2 m, out;
            m.x = TAU * v.x + cur[i].x;
            m.y = TAU * v.y + cur[i].y;
            out.x = (m.x >= V_TH) ? 1.f : 0.f;
            out.y = (m.y >= V_TH) ? 1.f : 0.f;
            v.x = (m.x >= V_TH) ? 0.f : m.x;
            v.y = (m.y >= V_TH) ? 0.f : m.y;
            __builtin_nontemporal_store(out, yp + (size_t)(c * CHUNK + i) * n2);
        }
        #pragma unroll
        for (int i = 0; i < CHUNK; ++i)
            cur[i] = nxt[i];
    }
}

extern "C" void kernel_launch(void* const* d_in, const int* in_sizes, int n_in,
                              void* d_out, int out_size, void* d_ws, size_t ws_size,
                              hipStream_t stream) {
    const float* x = (const float*)d_in[0];
    float* y = (float*)d_out;

    int total = in_sizes[0];        // T*B*N = 33554432
    int per_t = total / T_STEPS;    // B*N   = 1048576
    int n2 = per_t / 2;             // 524288 float2 chains

    const int block = 256;
    int grid = (n2 + block - 1) / block;  // 2048 blocks -> 32 waves/CU
    lif_btn_kernel<<<grid, block, 0, stream>>>(
        (const f32x2*)x, (f32x2*)y, n2);
}

// Round 6
// 46.286 us; speedup vs baseline: 1.1805x; 1.1805x over previous
//
#include <hip/hip_runtime.h>

// LIF_BTN: y[t] = heaviside(tau*v[t-1] + x[t] - v_th), v[t] = (spike ? 0 : m)
// x: [T=32, B=32, N=32768] f32; y same. Memory-bound: 131 MB compulsory HBM
// writes + ~67 MB HBM reads (L3 serves other half of x; harness memsets thrash
// the rest - not kernel-addressable). Floor ~32 us @ 6.3 TB/s.
// R5: distance-8 rotating pipeline, fully unrolled: per timestep issue exactly
// {load t+8, compute t, nt-store t}. Same 8-deep MLP as R2 (best, 43.9 us) but
// finest possible read/write interleave; R4 showed bulk read/write phase
// bunching costs ~20% (DRAM direction turnaround across lockstep waves).

typedef float f32x2 __attribute__((ext_vector_type(2)));

#define T_STEPS 32
#define DEPTH 8
#define TAU 0.5f
#define V_TH 1.0f

__global__ __launch_bounds__(256) void lif_btn_kernel(
    const f32x2* __restrict__ x, f32x2* __restrict__ y, int n2) {
    int idx = blockIdx.x * blockDim.x + threadIdx.x;
    if (idx >= n2) return;

    const f32x2* xp = x + idx;
    f32x2* yp = y + idx;

    f32x2 v;
    v.x = 0.f; v.y = 0.f;

    f32x2 buf[DEPTH];

    // prologue: fill the pipeline
    #pragma unroll
    for (int t = 0; t < DEPTH; ++t)
        buf[t] = xp[(size_t)t * n2];

    // steady state: 1 load + 1 compute + 1 store per step (all indices
    // compile-time after full unroll -> buf stays in VGPRs)
    #pragma unroll
    for (int t = 0; t < T_STEPS; ++t) {
        f32x2 xt = buf[t & (DEPTH - 1)];
        if (t + DEPTH < T_STEPS)
            buf[t & (DEPTH - 1)] = xp[(size_t)(t + DEPTH) * n2];

        f32x2 m, out;
        m.x = TAU * v.x + xt.x;
        m.y = TAU * v.y + xt.y;
        out.x = (m.x >= V_TH) ? 1.f : 0.f;
        out.y = (m.y >= V_TH) ? 1.f : 0.f;
        v.x = (m.x >= V_TH) ? 0.f : m.x;
        v.y = (m.y >= V_TH) ? 0.f : m.y;
        __builtin_nontemporal_store(out, yp + (size_t)t * n2);
    }
}

extern "C" void kernel_launch(void* const* d_in, const int* in_sizes, int n_in,
                              void* d_out, int out_size, void* d_ws, size_t ws_size,
                              hipStream_t stream) {
    const float* x = (const float*)d_in[0];
    float* y = (float*)d_out;

    int total = in_sizes[0];        // T*B*N = 33554432
    int per_t = total / T_STEPS;    // B*N   = 1048576
    int n2 = per_t / 2;             // 524288 float2 chains

    const int block = 256;
    int grid = (n2 + block - 1) / block;  // 2048 blocks -> 32 waves/CU
    lif_btn_kernel<<<grid, block, 0, stream>>>(
        (const f32x2*)x, (f32x2*)y, n2);
}